// Round 2
// baseline (432.829 us; speedup 1.0000x reference)
//
#include <hip/hip_runtime.h>

typedef __attribute__((ext_vector_type(8))) short bf16x8;
typedef __attribute__((ext_vector_type(4))) float f32x4;
typedef unsigned short u16;
typedef unsigned int u32;

#define DI __device__ __forceinline__

// Problem constants: B=8, A=1024, NB=64, NAB=NF=128, NG=25, NI=3
constexpr int ATOMS = 8192;   // B*A

DI float b2f(u16 u){ union{u32 i; float f;} v; v.i = ((u32)u)<<16; return v.f; }
DI u16 f2b(float f){ union{float f; u32 i;} v; v.f=f; u32 u=v.i;
                     return (u16)((u + 0x7fffu + ((u>>16)&1u))>>16); }
// dtype-agnostic input load (element index): isbf ? bf16 : f32
DI float ldin(const void* p, size_t i, int isbf){
  return isbf ? b2f(((const u16*)p)[i]) : ((const float*)p)[i];
}
DI float sspf(float x){           // shifted softplus: softplus(x) - ln2
  float ax = fabsf(x);
  return fmaxf(x,0.f) + __logf(1.f + __expf(-ax)) - 0.6931471805599453f;
}
DI f32x4 mfma16(bf16x8 a, bf16x8 b, f32x4 c){
  return __builtin_amdgcn_mfma_f32_16x16x32_bf16(a,b,c,0,0,0);
}
// Build an A-fragment (8 consecutive k as bf16) from fp32 global memory
DI bf16x8 ldfragA_f32(const float* p){
  const f32x4* pp = (const f32x4*)p;
  f32x4 a = pp[0], b = pp[1];
  bf16x8 r;
  r[0]=(short)f2b(a[0]); r[1]=(short)f2b(a[1]); r[2]=(short)f2b(a[2]); r[3]=(short)f2b(a[3]);
  r[4]=(short)f2b(b[0]); r[5]=(short)f2b(b[1]); r[6]=(short)f2b(b[2]); r[7]=(short)f2b(b[3]);
  return r;
}

// ---------------------------------------------------------------------------
// dtype probe: neighbor_mask is all ones. bf16 -> u16[0]==0x3F80; f32 -> 0x0000.
__global__ void k_flag(const u16* __restrict__ nm, int* __restrict__ flag){
  if(threadIdx.x==0) *flag = (nm[0]==0x3F80u) ? 1 : 0;
}

// ---------------------------------------------------------------------------
__global__ __launch_bounds__(256) void k_embed(const void* __restrict__ emb,
                                               const int* __restrict__ z,
                                               float* __restrict__ X,
                                               const int* __restrict__ flag){
  int isbf = *flag;
  int idx = blockIdx.x*256 + threadIdx.x;        // < ATOMS*128
  int a = idx>>7, f = idx&127;
  X[idx] = ldin(emb, (size_t)z[a]*128 + f, isbf);
}

// ---------------------------------------------------------------------------
// Per-pair distances: R = r_ij (fp32), CM = cutoff(r)*mask (fp32).
__global__ __launch_bounds__(256) void k_dist(const void* __restrict__ pos,
                                              const void* __restrict__ cell,
                                              const void* __restrict__ cello,
                                              const void* __restrict__ nmask,
                                              const int* __restrict__ nbrs,
                                              float* __restrict__ R,
                                              float* __restrict__ CM,
                                              const int* __restrict__ flag){
  int isbf = *flag;
  int pairIdx = blockIdx.x*256 + threadIdx.x;    // < ATOMS*64
  int atom = pairIdx>>6;
  int b = atom>>10;
  int nb = nbrs[pairIdx];
  int jrow = (b<<10) + nb;

  float pi0=ldin(pos,atom*3+0,isbf), pi1=ldin(pos,atom*3+1,isbf), pi2=ldin(pos,atom*3+2,isbf);
  float pj0=ldin(pos,jrow*3+0,isbf), pj1=ldin(pos,jrow*3+1,isbf), pj2=ldin(pos,jrow*3+2,isbf);
  float co0=ldin(cello,(size_t)pairIdx*3+0,isbf),
        co1=ldin(cello,(size_t)pairIdx*3+1,isbf),
        co2=ldin(cello,(size_t)pairIdx*3+2,isbf);
  size_t cb = (size_t)b*9;
  pj0 += co0*ldin(cell,cb+0,isbf) + co1*ldin(cell,cb+3,isbf) + co2*ldin(cell,cb+6,isbf);
  pj1 += co0*ldin(cell,cb+1,isbf) + co1*ldin(cell,cb+4,isbf) + co2*ldin(cell,cb+7,isbf);
  pj2 += co0*ldin(cell,cb+2,isbf) + co1*ldin(cell,cb+5,isbf) + co2*ldin(cell,cb+8,isbf);
  float d0 = pj0-pi0, d1 = pj1-pi1, d2 = pj2-pi2;
  float dd = d0*d0 + d1*d1 + d2*d2;
  float m  = ldin(nmask,pairIdx,isbf);
  float r  = sqrtf(m>0.f ? dd : 1.f) * m;
  R[pairIdx] = r;
  float c = 0.5f*(__cosf(r*3.14159265358979f/5.f)+1.f) * ((r<5.f)?1.f:0.f) * m;
  CM[pairIdx] = c;
}

// ---------------------------------------------------------------------------
// Pre-convert weight matrices into B-fragment-linear layout.
// frag(kk,t): elem[lane][j] = W[kk*32+q*8+j][t*16+(lane&15)]
__global__ __launch_bounds__(64) void k_wfrag(const void* __restrict__ fw1,
                                              const void* __restrict__ fw2,
                                              const void* __restrict__ in2f,
                                              const void* __restrict__ f2o,
                                              const void* __restrict__ den,
                                              u16* __restrict__ dst,
                                              const int* __restrict__ flag){
  int isbf = *flag;
  int wid = blockIdx.x;                // 0..407  (3 interactions x 136 frags)
  int lane = threadIdx.x;
  int q = lane>>4, l15 = lane&15;
  int i = wid/136, r = wid%136;
  int mat, kk, t;
  if(r < 8){ mat=0; kk=0; t=r; }
  else { int r2 = r-8; mat = 1 + (r2>>5); kk = (r2>>3)&3; t = r2&7; }
  const void* src; size_t sbase; int K; int off;
  switch(mat){
    case 0:  src = fw1;  sbase=(size_t)i*3200;  K=25;  off=0;     break;
    case 1:  src = fw2;  sbase=(size_t)i*16384; K=128; off=4096;  break;
    case 2:  src = in2f; sbase=(size_t)i*16384; K=128; off=20480; break;
    case 3:  src = f2o;  sbase=(size_t)i*16384; K=128; off=36864; break;
    default: src = den;  sbase=(size_t)i*16384; K=128; off=53248; break;
  }
  int c = t*16 + l15;
  bf16x8 frag;
  #pragma unroll
  for(int j=0;j<8;j++){
    int k = kk*32 + q*8 + j;
    float v = (k<K) ? ldin(src, sbase + (size_t)k*128 + c, isbf) : 0.f;
    frag[j] = (short)f2b(v);
  }
  *(bf16x8*)(dst + (size_t)i*69632 + off + ((kk*8+t)*64 + lane)*8) = frag;
}

// ---------------------------------------------------------------------------
// y = x @ in2f (iteration 0 only).  One wave per 16 rows; K=128 (4 ktiles).
__global__ __launch_bounds__(128) void k_proj(const float* __restrict__ X,
                                              const u16* __restrict__ wf,
                                              float* __restrict__ Y){
  int wid = blockIdx.x*2 + (threadIdx.x>>6);
  int lane = threadIdx.x & 63;
  int q = lane>>4, l15 = lane&15;
  int row0 = wid*16;
  f32x4 acc[8];
  #pragma unroll
  for(int t=0;t<8;t++) acc[t] = (f32x4){0.f,0.f,0.f,0.f};
  #pragma unroll
  for(int kk=0;kk<4;kk++){
    bf16x8 af = ldfragA_f32(X + (size_t)(row0+l15)*128 + kk*32 + q*8);
    #pragma unroll
    for(int t=0;t<8;t++){
      bf16x8 bf = *(const bf16x8*)(wf + ((kk*8+t)*64 + lane)*8);
      acc[t] = mfma16(af, bf, acc[t]);
    }
  }
  #pragma unroll
  for(int t=0;t<8;t++){
    #pragma unroll
    for(int r=0;r<4;r++)
      Y[(size_t)(row0 + q*4 + r)*128 + t*16 + l15] = acc[t][r];
  }
}

// ---------------------------------------------------------------------------
// CFConv: one wave per atom; gaussian A-frag regenerated from R on the fly.
__global__ __launch_bounds__(256) void k_cfconv(const float* __restrict__ R,
                                                const float* __restrict__ CM,
                                                const float* __restrict__ Y,
                                                const int* __restrict__ nbrs,
                                                const u16* __restrict__ fw1f,
                                                const u16* __restrict__ fw2f,
                                                const void* __restrict__ fb1,
                                                const void* __restrict__ fb2,
                                                float* __restrict__ AGG,
                                                int iidx,
                                                const int* __restrict__ flag){
  __shared__ __align__(16) u16 Hbuf[4][16][136];   // per-wave 16x128 tile, +8 pad
  int isbf = *flag;
  int widx = threadIdx.x>>6;
  int lane = threadIdx.x & 63;
  int q = lane>>4, l15 = lane&15;
  int atom = blockIdx.x*4 + widx;
  int bbase = atom & ~1023;            // batch row base for y gather
  u16 (*H)[136] = Hbuf[widx];

  bf16x8 w1f[8];
  #pragma unroll
  for(int t=0;t<8;t++) w1f[t] = *(const bf16x8*)(fw1f + (size_t)t*512 + lane*8);
  float fb1v[8], fb2v[8];
  #pragma unroll
  for(int t=0;t<8;t++){
    fb1v[t]=ldin(fb1,(size_t)iidx*128 + t*16+l15,isbf);
    fb2v[t]=ldin(fb2,(size_t)iidx*128 + t*16+l15,isbf);
  }
  float aggp[8];
  #pragma unroll
  for(int t=0;t<8;t++) aggp[t]=0.f;

  const float width = 5.0f/24.0f;
  const float coeff = -0.5f/(width*width);

  for(int mt=0; mt<4; mt++){
    asm volatile("s_waitcnt lgkmcnt(0)" ::: "memory");
    // gaussian A-frag: row = l15 (neighbor mt*16+l15), k = q*8+j
    float r = R[(size_t)atom*64 + mt*16 + l15];
    bf16x8 af;
    #pragma unroll
    for(int j=0;j<8;j++){
      int k = q*8 + j;
      float v = 0.f;
      if(k < 25){ float t = r - (float)k*width; v = __expf(coeff*t*t); }
      af[j] = (short)f2b(v);
    }
    f32x4 acc[8];
    #pragma unroll
    for(int t=0;t<8;t++) acc[t] = mfma16(af, w1f[t], (f32x4){0.f,0.f,0.f,0.f});
    #pragma unroll
    for(int t=0;t<8;t++){
      #pragma unroll
      for(int r2=0;r2<4;r2++){
        float h = sspf(acc[t][r2] + fb1v[t]);
        H[q*4+r2][t*16+l15] = f2b(h);
      }
    }
    asm volatile("s_waitcnt lgkmcnt(0)" ::: "memory");
    #pragma unroll
    for(int t=0;t<8;t++) acc[t] = (f32x4){0.f,0.f,0.f,0.f};
    #pragma unroll
    for(int kk=0;kk<4;kk++){
      bf16x8 a2 = *(const bf16x8*)(&H[l15][kk*32 + q*8]);
      #pragma unroll
      for(int t=0;t<8;t++){
        bf16x8 bf = *(const bf16x8*)(fw2f + ((kk*8+t)*64 + lane)*8);
        acc[t] = mfma16(a2, bf, acc[t]);
      }
    }
    f32x4 cmv = *(const f32x4*)(CM + (size_t)atom*64 + mt*16 + q*4);
    int4  nb4 = *(const int4*)(nbrs + (size_t)atom*64 + mt*16 + q*4);
    #pragma unroll
    for(int t=0;t<8;t++){
      int col = t*16 + l15;
      aggp[t] = fmaf((acc[t][0]+fb2v[t])*cmv[0], Y[(size_t)(bbase+nb4.x)*128+col], aggp[t]);
      aggp[t] = fmaf((acc[t][1]+fb2v[t])*cmv[1], Y[(size_t)(bbase+nb4.y)*128+col], aggp[t]);
      aggp[t] = fmaf((acc[t][2]+fb2v[t])*cmv[2], Y[(size_t)(bbase+nb4.z)*128+col], aggp[t]);
      aggp[t] = fmaf((acc[t][3]+fb2v[t])*cmv[3], Y[(size_t)(bbase+nb4.w)*128+col], aggp[t]);
    }
  }
  #pragma unroll
  for(int t=0;t<8;t++){
    float v = aggp[t];
    v += __shfl_xor(v, 16, 64);
    v += __shfl_xor(v, 32, 64);
    aggp[t] = v;
  }
  if(q==0){
    #pragma unroll
    for(int t=0;t<8;t++) AGG[(size_t)atom*128 + t*16 + l15] = aggp[t];
  }
}

// ---------------------------------------------------------------------------
// v = ssp(agg @ f2out + b) @ dense + b;  x += v;  (if !last) y = x @ in2f_next
__global__ __launch_bounds__(128) void k_out(const float* __restrict__ AGG,
                                             float* __restrict__ X,
                                             float* __restrict__ Y,
                                             const u16* __restrict__ f2of,
                                             const u16* __restrict__ denf,
                                             const u16* __restrict__ in2fN,
                                             const void* __restrict__ f2ob,
                                             const void* __restrict__ denb,
                                             void* __restrict__ OUT,
                                             int last, int iidx,
                                             const int* __restrict__ flag){
  __shared__ __align__(16) u16 Tb[2][16][136];
  __shared__ __align__(16) u16 Xb[2][16][136];
  int isbf = *flag;
  int widx = threadIdx.x>>6;
  int lane = threadIdx.x & 63;
  int q = lane>>4, l15 = lane&15;
  int row0 = (blockIdx.x*2 + widx)*16;
  u16 (*T)[136]  = Tb[widx];
  u16 (*Xw)[136] = Xb[widx];

  // G1: ssp(agg @ f2out + b)
  f32x4 acc[8];
  #pragma unroll
  for(int t=0;t<8;t++) acc[t] = (f32x4){0.f,0.f,0.f,0.f};
  #pragma unroll
  for(int kk=0;kk<4;kk++){
    bf16x8 af = ldfragA_f32(AGG + (size_t)(row0+l15)*128 + kk*32 + q*8);
    #pragma unroll
    for(int t=0;t<8;t++){
      bf16x8 bf = *(const bf16x8*)(f2of + ((kk*8+t)*64 + lane)*8);
      acc[t] = mfma16(af, bf, acc[t]);
    }
  }
  #pragma unroll
  for(int t=0;t<8;t++){
    float bv = ldin(f2ob,(size_t)iidx*128 + t*16+l15,isbf);
    #pragma unroll
    for(int r=0;r<4;r++) T[q*4+r][t*16+l15] = f2b(sspf(acc[t][r] + bv));
  }
  asm volatile("s_waitcnt lgkmcnt(0)" ::: "memory");

  // G2: @ dense + b + x  (residual)
  #pragma unroll
  for(int t=0;t<8;t++) acc[t] = (f32x4){0.f,0.f,0.f,0.f};
  #pragma unroll
  for(int kk=0;kk<4;kk++){
    bf16x8 a2 = *(const bf16x8*)(&T[l15][kk*32 + q*8]);
    #pragma unroll
    for(int t=0;t<8;t++){
      bf16x8 bf = *(const bf16x8*)(denf + ((kk*8+t)*64 + lane)*8);
      acc[t] = mfma16(a2, bf, acc[t]);
    }
  }
  #pragma unroll
  for(int t=0;t<8;t++){
    int col = t*16 + l15;
    float bv = ldin(denb,(size_t)iidx*128 + col,isbf);
    #pragma unroll
    for(int r=0;r<4;r++){
      size_t idx = (size_t)(row0 + q*4 + r)*128 + col;
      float xn = X[idx] + acc[t][r] + bv;
      X[idx] = xn;
      if(last){
        if(isbf) ((u16*)OUT)[idx] = f2b(xn);
        else     ((float*)OUT)[idx] = xn;
      } else {
        Xw[q*4+r][col] = f2b(xn);
      }
    }
  }
  if(!last){
    asm volatile("s_waitcnt lgkmcnt(0)" ::: "memory");
    // G3: y = x_new @ in2f_next
    #pragma unroll
    for(int t=0;t<8;t++) acc[t] = (f32x4){0.f,0.f,0.f,0.f};
    #pragma unroll
    for(int kk=0;kk<4;kk++){
      bf16x8 a2 = *(const bf16x8*)(&Xw[l15][kk*32 + q*8]);
      #pragma unroll
      for(int t=0;t<8;t++){
        bf16x8 bf = *(const bf16x8*)(in2fN + ((kk*8+t)*64 + lane)*8);
        acc[t] = mfma16(a2, bf, acc[t]);
      }
    }
    #pragma unroll
    for(int t=0;t<8;t++){
      #pragma unroll
      for(int r=0;r<4;r++)
        Y[(size_t)(row0 + q*4 + r)*128 + t*16 + l15] = acc[t][r];
    }
  }
}

// ---------------------------------------------------------------------------
extern "C" void kernel_launch(void* const* d_in, const int* in_sizes, int n_in,
                              void* d_out, int out_size, void* d_ws, size_t ws_size,
                              hipStream_t stream){
  const void* pos   = d_in[0];
  const void* cell  = d_in[1];
  const void* cello = d_in[2];
  const void* nmask = d_in[3];
  // d_in[4] atom_mask: unused by the output
  const void* emb   = d_in[5];
  const void* fw1   = d_in[6];
  const void* fb1   = d_in[7];
  const void* fw2   = d_in[8];
  const void* fb2   = d_in[9];
  const void* in2f  = d_in[10];
  const void* f2o   = d_in[11];
  const void* f2ob  = d_in[12];
  const void* den   = d_in[13];
  const void* denb  = d_in[14];
  const int* z      = (const int*)d_in[15];
  const int* nbrs   = (const int*)d_in[16];

  char* ws = (char*)d_ws;
  float* X   = (float*)(ws);                 //  4 MB fp32 features
  float* Y   = (float*)(ws +  4194304);      //  4 MB projected features
  float* AGG = (float*)(ws +  8388608);      //  4 MB cfconv aggregate
  float* R   = (float*)(ws + 12582912);      //  2 MB distances
  float* CMp = (float*)(ws + 14680064);      //  2 MB cutoff*mask
  u16*   WF  = (u16*)  (ws + 16777216);      // 408 KB weight B-frags
  int*  flag = (int*)  (ws + 17825792);      // dtype flag

  k_flag <<<   1,  64, 0, stream>>>((const u16*)nmask, flag);
  k_embed<<<4096, 256, 0, stream>>>(emb, z, X, flag);
  k_dist <<<2048, 256, 0, stream>>>(pos, cell, cello, nmask, nbrs, R, CMp, flag);
  k_wfrag<<< 408,  64, 0, stream>>>(fw1, fw2, in2f, f2o, den, WF, flag);
  k_proj <<< 256, 128, 0, stream>>>(X, WF + 20480 /* in2f frags, i=0 */, Y);

  for(int i=0;i<3;i++){
    const u16* base = WF + (size_t)i*69632;
    k_cfconv<<<2048, 256, 0, stream>>>(R, CMp, Y, nbrs,
                                       base + 0      /* fw1 frags */,
                                       base + 4096   /* fw2 frags */,
                                       fb1, fb2, AGG, i, flag);
    const u16* in2fN = (i<2) ? (WF + (size_t)(i+1)*69632 + 20480) : WF;
    k_out<<<256, 128, 0, stream>>>(AGG, X, Y,
                                   base + 36864 /* f2out frags */,
                                   base + 53248 /* dense frags */,
                                   in2fN,
                                   f2ob, denb,
                                   d_out, (i==2) ? 1 : 0, i, flag);
  }
}